// Round 1
// baseline (219.822 us; speedup 1.0000x reference)
//
#include <hip/hip_runtime.h>

// PixelShuffle1d: x (8, 256, 16384) f32 -> out (8, 64, 65536) f32, upscale=4.
// out[b, c', l*4 + j] = x[b, c'*4 + j, l]
// Flattened with bc = b*64 + c' (both input and output have 65536 elems per bc):
//   out[bc*65536 + l*4 + j] = x[bc*65536 + j*16384 + l]
//
// One thread per (bc, l): 4 coalesced scalar loads (stride-1 in l across the
// wave within each of the 4 source rows) + one coalesced float4 store.

constexpr int L = 16384;        // input inner length
constexpr long TOTAL_QUADS = 8L * 64L * 16384L;  // 8.4M threads, one float4 out each

__global__ __launch_bounds__(256) void pixel_shuffle1d_kernel(
    const float* __restrict__ x, float* __restrict__ out) {
    long tid = (long)blockIdx.x * blockDim.x + threadIdx.x;
    if (tid >= TOTAL_QUADS) return;

    int l  = (int)(tid & (L - 1));   // position within row
    long bc = tid >> 14;             // b*64 + c'

    const float* src = x + bc * (4L * L) + l;
    float4 v;
    v.x = src[0L * L];
    v.y = src[1L * L];
    v.z = src[2L * L];
    v.w = src[3L * L];

    reinterpret_cast<float4*>(out)[tid] = v;
}

extern "C" void kernel_launch(void* const* d_in, const int* in_sizes, int n_in,
                              void* d_out, int out_size, void* d_ws, size_t ws_size,
                              hipStream_t stream) {
    const float* x = (const float*)d_in[0];
    float* out = (float*)d_out;

    const int block = 256;
    const long grid = (TOTAL_QUADS + block - 1) / block;  // 32768 blocks
    pixel_shuffle1d_kernel<<<(int)grid, block, 0, stream>>>(x, out);
}